// Round 1
// baseline (799.614 us; speedup 1.0000x reference)
//
#include <hip/hip_runtime.h>
#include <math.h>

// Problem dims (fixed by reference)
#define BB   8
#define TT   2048
#define CIN  512
#define DD   1024
#define MM   (BB * TT)     // 16384 rows for the GEMMs

// GEMM tiling
constexpr int BM = 64;
constexpr int BN = 128;
constexpr int BK = 16;

// softplus(z) = logaddexp(z, 0) — matches jax.nn.softplus / np.logaddexp
__device__ __forceinline__ float softplus_f(float z) {
    return fmaxf(z, 0.f) + log1pf(expf(-fabsf(z)));
}

// K1: fused dual GEMM  zd = x@Wd, zb = x@Wb  (+bias)  →  a_step, b_step
//   delta  = softplus(zd + bd)
//   a_step = exp(-delta * exp(A_log))
//   b_step = delta * (zb + bb)
__global__ __launch_bounds__(256) void k1_gemm_act(
    const float* __restrict__ x,      // [MM, CIN]
    const float* __restrict__ Wd,     // [CIN, DD]
    const float* __restrict__ Wb,     // [CIN, DD]
    const float* __restrict__ bd,     // [DD]
    const float* __restrict__ bb,     // [DD]
    const float* __restrict__ A_log,  // [DD]
    float* __restrict__ a_out,        // [MM, DD]
    float* __restrict__ b_out)        // [MM, DD]
{
    __shared__ float xs[BM][BK + 1];   // +1 pad: conflict-free column reads
    __shared__ float wds[BK][BN];
    __shared__ float wbs[BK][BN];

    const int tid = threadIdx.x;
    const int n0  = blockIdx.x * BN;
    const int m0  = blockIdx.y * BM;
    const int tx  = tid & 15;          // n-group: 16 groups * 8 cols
    const int ty  = tid >> 4;          // m-group: 16 groups * 4 rows

    float accd[4][8];
    float accb[4][8];
#pragma unroll
    for (int i = 0; i < 4; ++i)
#pragma unroll
        for (int j = 0; j < 8; ++j) { accd[i][j] = 0.f; accb[i][j] = 0.f; }

    // global-load index helpers
    const int lm = tid >> 2;           // 0..63   x-tile row
    const int lk = (tid & 3) * 4;      // 0,4,8,12 x-tile col (float4)
    const int wr = tid >> 4;           // 0..15   W-tile row
    const int wc = (tid & 15) * 8;     // 0..120  W-tile col (2x float4)

    for (int k0 = 0; k0 < CIN; k0 += BK) {
        float4 xv = *(const float4*)(x + (size_t)(m0 + lm) * CIN + k0 + lk);
        const float* wdp = Wd + (size_t)(k0 + wr) * DD + n0 + wc;
        const float* wbp = Wb + (size_t)(k0 + wr) * DD + n0 + wc;
        float4 wd0 = *(const float4*)(wdp);
        float4 wd1 = *(const float4*)(wdp + 4);
        float4 wb0 = *(const float4*)(wbp);
        float4 wb1 = *(const float4*)(wbp + 4);

        __syncthreads();   // previous tile's compute done
        xs[lm][lk + 0] = xv.x;
        xs[lm][lk + 1] = xv.y;
        xs[lm][lk + 2] = xv.z;
        xs[lm][lk + 3] = xv.w;
        *(float4*)&wds[wr][wc]     = wd0;
        *(float4*)&wds[wr][wc + 4] = wd1;
        *(float4*)&wbs[wr][wc]     = wb0;
        *(float4*)&wbs[wr][wc + 4] = wb1;
        __syncthreads();

#pragma unroll
        for (int kk = 0; kk < BK; ++kk) {
            float xf[4];
#pragma unroll
            for (int i = 0; i < 4; ++i) xf[i] = xs[ty * 4 + i][kk];
            float4 d0 = *(const float4*)&wds[kk][tx * 8];
            float4 d1 = *(const float4*)&wds[kk][tx * 8 + 4];
            float4 c0 = *(const float4*)&wbs[kk][tx * 8];
            float4 c1 = *(const float4*)&wbs[kk][tx * 8 + 4];
            float wdv[8] = {d0.x, d0.y, d0.z, d0.w, d1.x, d1.y, d1.z, d1.w};
            float wbv[8] = {c0.x, c0.y, c0.z, c0.w, c1.x, c1.y, c1.z, c1.w};
#pragma unroll
            for (int i = 0; i < 4; ++i) {
                const float xi = xf[i];
#pragma unroll
                for (int j = 0; j < 8; ++j) {
                    accd[i][j] = fmaf(xi, wdv[j], accd[i][j]);
                    accb[i][j] = fmaf(xi, wbv[j], accb[i][j]);
                }
            }
        }
    }

    // epilogue
    const int n = n0 + tx * 8;
    float4 bd0 = *(const float4*)(bd + n);
    float4 bd1 = *(const float4*)(bd + n + 4);
    float4 bb0 = *(const float4*)(bb + n);
    float4 bb1 = *(const float4*)(bb + n + 4);
    float4 al0 = *(const float4*)(A_log + n);
    float4 al1 = *(const float4*)(A_log + n + 4);
    float bdv[8] = {bd0.x, bd0.y, bd0.z, bd0.w, bd1.x, bd1.y, bd1.z, bd1.w};
    float bbv[8] = {bb0.x, bb0.y, bb0.z, bb0.w, bb1.x, bb1.y, bb1.z, bb1.w};
    float alv[8] = {al0.x, al0.y, al0.z, al0.w, al1.x, al1.y, al1.z, al1.w};
    float Av[8];
#pragma unroll
    for (int j = 0; j < 8; ++j) Av[j] = expf(alv[j]);

#pragma unroll
    for (int i = 0; i < 4; ++i) {
        const int m = m0 + ty * 4 + i;
        float av[8], bv[8];
#pragma unroll
        for (int j = 0; j < 8; ++j) {
            float zd    = accd[i][j] + bdv[j];
            float delta = softplus_f(zd);
            float zb    = accb[i][j] + bbv[j];
            av[j] = expf(-delta * Av[j]);
            bv[j] = delta * zb;
        }
        float* ap = a_out + (size_t)m * DD + n;
        float* bp = b_out + (size_t)m * DD + n;
        *(float4*)(ap)     = make_float4(av[0], av[1], av[2], av[3]);
        *(float4*)(ap + 4) = make_float4(av[4], av[5], av[6], av[7]);
        *(float4*)(bp)     = make_float4(bv[0], bv[1], bv[2], bv[3]);
        *(float4*)(bp + 4) = make_float4(bv[4], bv[5], bv[6], bv[7]);
    }
}

// K2: sequential spiking scan over T.  One thread per (batch, channel).
// h = a*h + b ; s = (h - thr > 0) ; h = s ? 0 : h
__global__ __launch_bounds__(64) void k2_scan(
    const float* __restrict__ a,     // [BB, TT, DD]
    const float* __restrict__ b,     // [BB, TT, DD]
    const float* __restrict__ thr,   // [DD]
    float* __restrict__ hout,        // [BB, TT, DD]  (d_out first half, scratch)
    float* __restrict__ sout)        // [BB, TT, DD]  (d_out second half)
{
    const int gid   = blockIdx.x * 64 + threadIdx.x;   // 0..8191
    const int batch = gid >> 10;
    const int d     = gid & (DD - 1);
    const float th  = thr[d];
    const size_t base = (size_t)batch * TT * DD + d;

    float h = 0.f;
#pragma unroll 8
    for (int t = 0; t < TT; ++t) {
        const size_t idx = base + (size_t)t * DD;
        const float av = a[idx];
        const float bv = b[idx];
        h = fmaf(av, h, bv);
        const bool spike = (h - th) > 0.f;
        const float s = spike ? 1.f : 0.f;
        h = spike ? 0.f : h;
        hout[idx] = h;
        sout[idx] = s;
    }
}

// K3: in-place LayerNorm over last dim (D=1024), one block per row.
__global__ __launch_bounds__(256) void k3_ln(
    float* __restrict__ h,           // [MM, DD]  in/out (d_out first half)
    const float* __restrict__ gamma,
    const float* __restrict__ beta)
{
    const int row = blockIdx.x;
    const int tid = threadIdx.x;
    const int lane = tid & 63;
    const int wid  = tid >> 6;

    __shared__ float red[4];
    __shared__ float bc[2];

    float* rp = h + (size_t)row * DD + tid * 4;
    float4 v = *(const float4*)rp;

    float s = v.x + v.y + v.z + v.w;
#pragma unroll
    for (int off = 32; off > 0; off >>= 1) s += __shfl_down(s, off);
    if (lane == 0) red[wid] = s;
    __syncthreads();
    if (tid == 0) bc[0] = (red[0] + red[1] + red[2] + red[3]) * (1.0f / DD);
    __syncthreads();
    const float mu = bc[0];

    float dx = v.x - mu, dy = v.y - mu, dz = v.z - mu, dw = v.w - mu;
    float ss = dx * dx + dy * dy + dz * dz + dw * dw;
#pragma unroll
    for (int off = 32; off > 0; off >>= 1) ss += __shfl_down(ss, off);
    __syncthreads();           // everyone past reading red before overwrite
    if (lane == 0) red[wid] = ss;
    __syncthreads();
    if (tid == 0) bc[1] = (red[0] + red[1] + red[2] + red[3]) * (1.0f / DD);
    __syncthreads();
    const float inv = 1.0f / sqrtf(bc[1] + 1e-5f);

    float4 g  = *(const float4*)(gamma + tid * 4);
    float4 be = *(const float4*)(beta + tid * 4);
    float4 o;
    o.x = dx * inv * g.x + be.x;
    o.y = dy * inv * g.y + be.y;
    o.z = dz * inv * g.z + be.z;
    o.w = dw * inv * g.w + be.w;
    *(float4*)rp = o;
}

extern "C" void kernel_launch(void* const* d_in, const int* in_sizes, int n_in,
                              void* d_out, int out_size, void* d_ws, size_t ws_size,
                              hipStream_t stream) {
    const float* x     = (const float*)d_in[0];
    const float* Wd    = (const float*)d_in[1];
    const float* bd    = (const float*)d_in[2];
    const float* Wb    = (const float*)d_in[3];
    const float* bb    = (const float*)d_in[4];
    const float* A_log = (const float*)d_in[5];
    const float* thr   = (const float*)d_in[6];
    const float* gamma = (const float*)d_in[7];
    const float* beta  = (const float*)d_in[8];

    float* out    = (float*)d_out;                    // [MM, DD] LN output
    float* spikes = out + (size_t)MM * DD;            // [MM, DD]
    float* a_ws   = (float*)d_ws;                     // [MM, DD]
    float* b_ws   = a_ws + (size_t)MM * DD;           // [MM, DD]

    dim3 g1(DD / BN, MM / BM);                        // (8, 256)
    k1_gemm_act<<<g1, 256, 0, stream>>>(x, Wd, Wb, bd, bb, A_log, a_ws, b_ws);

    // scan writes h_post into d_out's first half (LN runs in-place after)
    k2_scan<<<(BB * DD) / 64, 64, 0, stream>>>(a_ws, b_ws, thr, out, spikes);

    k3_ln<<<MM, 256, 0, stream>>>(out, gamma, beta);
}